// Round 2
// baseline (370.384 us; speedup 1.0000x reference)
//
#include <hip/hip_runtime.h>

// AutoregressiveDecoder: B=2048, T=1024, D=32, S=2
//   out[b,0]   = init_states[b]
//   out[b,t]   = Ws @ out[b,t-1] + Wz @ z[b,t-1],  t = 1..1023
// Linear recurrence with constant 2x2 A=Ws -> chunked parallel scan.
// One block per batch. 32 chunks x 32 steps.
//   phase 1: v_r = Wz @ z[b,r]  (all HBM traffic, coalesced float4 + shfl reduce)
//   phase 2: 32 local scans in LDS (in-place), A-power table, carry chain
//   phase 3: out[b,t] = l_{t-1} + A^i * carry_c   (coalesced float2 stores)

#define BB 2048
#define TT 1024
#define DD 32

__global__ __launch_bounds__(256, 8)
void ar_decoder_kernel(const float* __restrict__ init_states,
                       const float* __restrict__ z,
                       const float* __restrict__ W,
                       float* __restrict__ out)
{
    // padded v/l buffer: row r stored at r + (r>>5)  (max 1022+31=1053)
    __shared__ float2 vbuf[1056];
    __shared__ float2 finals[32];
    __shared__ float2 carry[32];
    __shared__ float4 apow[32];   // apow[c] = A^(c+1), row-major {m00,m01,m10,m11}

    const int tid = threadIdx.x;
    const int b   = blockIdx.x;
    const int j   = tid & 7;    // float4 slot within row (d = 4j..4j+3)
    const int q   = tid >> 3;   // row-group 0..31

    // A = Ws (row-major 2x2); W is (2, 34) row-major: Ws = cols 0..1, Wz = cols 2..33
    const float A00 = W[0],  A01 = W[1];
    const float A10 = W[34], A11 = W[35];

    // per-thread Wz weights for its d-quad
    const float w00 = W[2  + 4*j + 0], w01 = W[2  + 4*j + 1];
    const float w02 = W[2  + 4*j + 2], w03 = W[2  + 4*j + 3];
    const float w10 = W[36 + 4*j + 0], w11 = W[36 + 4*j + 1];
    const float w12 = W[36 + 4*j + 2], w13 = W[36 + 4*j + 3];

    // ---- phase 1: v_r = Wz @ z[b,r] for r = 0..1022 ----
    const float4* zb = reinterpret_cast<const float4*>(z + (size_t)b * TT * DD);
    #pragma unroll 4
    for (int m = 0; m < 32; ++m) {
        const int r = 32 * m + q;           // row handled by this 8-lane group
        if (r < TT - 1) {
            const float4 zv = zb[r * 8 + j];   // wave reads 1KB contiguous
            float p0 = zv.x*w00 + zv.y*w01 + zv.z*w02 + zv.w*w03;
            float p1 = zv.x*w10 + zv.y*w11 + zv.z*w12 + zv.w*w13;
            p0 += __shfl_xor(p0, 1, 8);  p1 += __shfl_xor(p1, 1, 8);
            p0 += __shfl_xor(p0, 2, 8);  p1 += __shfl_xor(p1, 2, 8);
            p0 += __shfl_xor(p0, 4, 8);  p1 += __shfl_xor(p1, 4, 8);
            if (j == 0) vbuf[r + (r >> 5)] = make_float2(p0, p1);
        }
    }
    __syncthreads();

    // ---- phase 2: local scans (in place) + A-power table ----
    if (tid < 32) {
        const int c  = tid;
        const int n  = (c == 31) ? 31 : 32;   // chunk 31 covers t=993..1023
        float s0 = 0.f, s1 = 0.f;
        for (int k = 0; k < n; ++k) {
            const int p = 33 * c + k;          // padded index of row 32c+k
            const float2 v = vbuf[p];
            const float ns0 = fmaf(A00, s0, fmaf(A01, s1, v.x));
            const float ns1 = fmaf(A10, s0, fmaf(A11, s1, v.y));
            s0 = ns0; s1 = ns1;
            vbuf[p] = make_float2(s0, s1);     // l_{k+1}
        }
        finals[c] = make_float2(s0, s1);
        // A^(c+1)
        float m00 = A00, m01 = A01, m10 = A10, m11 = A11;
        for (int k = 0; k < c; ++k) {
            const float t00 = A00*m00 + A01*m10;
            const float t01 = A00*m01 + A01*m11;
            const float t10 = A10*m00 + A11*m10;
            const float t11 = A10*m01 + A11*m11;
            m00 = t00; m01 = t01; m10 = t10; m11 = t11;
        }
        apow[c] = make_float4(m00, m01, m10, m11);
    }
    __syncthreads();

    // ---- carry chain: carry_c = state at t = 32c ----
    if (tid == 0) {
        float c0 = init_states[2 * b], c1 = init_states[2 * b + 1];
        out[(size_t)b * TT * 2 + 0] = c0;      // out[b,0] = init state
        out[(size_t)b * TT * 2 + 1] = c1;
        carry[0] = make_float2(c0, c1);
        const float4 A32 = apow[31];           // A^32
        for (int c = 0; c < 31; ++c) {
            const float2 f = finals[c];
            const float n0 = fmaf(A32.x, c0, fmaf(A32.y, c1, f.x));
            const float n1 = fmaf(A32.z, c0, fmaf(A32.w, c1, f.y));
            c0 = n0; c1 = n1;
            carry[c + 1] = make_float2(c0, c1);
        }
    }
    __syncthreads();

    // ---- phase 3: out[b,t] = l_{t-1} + A^i * carry_c ----
    // thread tid handles t = tid+1 + 256k; i = (t-1)&31 + 1 is k-invariant.
    const float4 M = apow[tid & 31];           // A^i
    float2* outb = reinterpret_cast<float2*>(out + (size_t)b * TT * 2);
    #pragma unroll
    for (int k = 0; k < 4; ++k) {
        const int t = tid + 1 + 256 * k;
        if (t < TT) {
            const int r = t - 1;
            const int c = r >> 5;
            const float2 l  = vbuf[r + (r >> 5)];
            const float2 cr = carry[c];
            const float o0 = fmaf(M.x, cr.x, fmaf(M.y, cr.y, l.x));
            const float o1 = fmaf(M.z, cr.x, fmaf(M.w, cr.y, l.y));
            outb[t] = make_float2(o0, o1);     // consecutive lanes -> contiguous
        }
    }
}

extern "C" void kernel_launch(void* const* d_in, const int* in_sizes, int n_in,
                              void* d_out, int out_size, void* d_ws, size_t ws_size,
                              hipStream_t stream) {
    const float* init = (const float*)d_in[0];
    const float* z    = (const float*)d_in[1];
    const float* W    = (const float*)d_in[2];
    float*       o    = (float*)d_out;
    ar_decoder_kernel<<<BB, 256, 0, stream>>>(init, z, W, o);
}

// Round 4
// 342.966 us; speedup vs baseline: 1.0799x; 1.0799x over previous
//
#include <hip/hip_runtime.h>

// AutoregressiveDecoder: B=2048, T=1024, D=32, S=2
//   out[b,0] = init_states[b];  out[b,t] = Ws@out[b,t-1] + Wz@z[b,t-1]
// Chunked parallel scan (32 chunks x 32 steps), one block per batch row.
//   phase 1: v_r = Wz @ z[b,r]          (all HBM traffic; coalesced float4 + shfl)
//   phase 2: wave0 = 32 local scans in LDS; wave1 = A-power table (concurrent)
//   phase 2b: Kogge-Stone carry scan over affine (2x2 M, f) pairs (5 shfl steps)
//   phase 3: out[b,t] = l_{t-1} + A^i * carry_c   (coalesced float2 stores)

#define BB 2048
#define TT 1024
#define DD 32

typedef float fx4 __attribute__((ext_vector_type(4)));  // nontemporal-load-able

__global__ __launch_bounds__(256)   // no min-wave force: avoid VGPR cap/spills
void ar_decoder_kernel(const float* __restrict__ init_states,
                       const float* __restrict__ z,
                       const float* __restrict__ W,
                       float* __restrict__ out)
{
    // padded v/l buffer: row r at r + (r>>5); bank stride 33*8B -> 2-way (free)
    __shared__ float2 vbuf[1056];
    __shared__ float2 carry[32];
    __shared__ float4 apow[32];   // apow[c] = A^(c+1) row-major {m00,m01,m10,m11}

    const int tid = threadIdx.x;
    const int b   = blockIdx.x;
    const int j   = tid & 7;    // float4 slot within row (d = 4j..4j+3)
    const int q   = tid >> 3;   // row-group 0..31

    // W is (2, 34) row-major: Ws = cols 0..1 (A), Wz = cols 2..33
    const float A00 = W[0],  A01 = W[1];
    const float A10 = W[34], A11 = W[35];
    // init state (broadcast-ish load, issued early)
    const float i0 = init_states[2 * b], i1 = init_states[2 * b + 1];

    const float w00 = W[2  + 4*j + 0], w01 = W[2  + 4*j + 1];
    const float w02 = W[2  + 4*j + 2], w03 = W[2  + 4*j + 3];
    const float w10 = W[36 + 4*j + 0], w11 = W[36 + 4*j + 1];
    const float w12 = W[36 + 4*j + 2], w13 = W[36 + 4*j + 3];

    // ---- phase 1: v_r = Wz @ z[b,r], r = 0..1022 ----
    const fx4* zb = reinterpret_cast<const fx4*>(z + (size_t)b * TT * DD);
    #pragma unroll 8
    for (int m = 0; m < 31; ++m) {          // branch-free main body
        const int r = 32 * m + q;
        const fx4 zv = __builtin_nontemporal_load(&zb[r * 8 + j]);
        float p0 = zv.x*w00 + zv.y*w01 + zv.z*w02 + zv.w*w03;
        float p1 = zv.x*w10 + zv.y*w11 + zv.z*w12 + zv.w*w13;
        p0 += __shfl_xor(p0, 1, 8);  p1 += __shfl_xor(p1, 1, 8);
        p0 += __shfl_xor(p0, 2, 8);  p1 += __shfl_xor(p1, 2, 8);
        p0 += __shfl_xor(p0, 4, 8);  p1 += __shfl_xor(p1, 4, 8);
        if (j == 0) vbuf[r + (r >> 5)] = make_float2(p0, p1);
    }
    {   // tail m = 31: rows 992+q, skip r = 1023
        const int r = 32 * 31 + q;
        if (q < 31) {
            const fx4 zv = __builtin_nontemporal_load(&zb[r * 8 + j]);
            float p0 = zv.x*w00 + zv.y*w01 + zv.z*w02 + zv.w*w03;
            float p1 = zv.x*w10 + zv.y*w11 + zv.z*w12 + zv.w*w13;
            p0 += __shfl_xor(p0, 1, 8);  p1 += __shfl_xor(p1, 1, 8);
            p0 += __shfl_xor(p0, 2, 8);  p1 += __shfl_xor(p1, 2, 8);
            p0 += __shfl_xor(p0, 4, 8);  p1 += __shfl_xor(p1, 4, 8);
            if (j == 0) vbuf[r + (r >> 5)] = make_float2(p0, p1);
        }
    }
    __syncthreads();

    // ---- phase 2: local scans (wave 0) || A-power table (wave 1) ----
    float f0 = 0.f, f1 = 0.f;               // lane-local chunk final (wave 0)
    if (tid < 32) {
        const int c = tid;
        const int n = (c == 31) ? 31 : 32;
        float s0 = 0.f, s1 = 0.f;
        for (int k = 0; k < n; ++k) {
            const int p = 33 * c + k;
            const float2 v = vbuf[p];
            const float ns0 = fmaf(A00, s0, fmaf(A01, s1, v.x));
            const float ns1 = fmaf(A10, s0, fmaf(A11, s1, v.y));
            s0 = ns0; s1 = ns1;
            vbuf[p] = make_float2(s0, s1);
        }
        f0 = s0; f1 = s1;
    } else if (tid < 64) {
        const int c = tid - 32;              // apow[c] = A^(c+1), on wave 1
        float m00 = A00, m01 = A01, m10 = A10, m11 = A11;
        for (int k = 0; k < c; ++k) {
            const float t00 = A00*m00 + A01*m10;
            const float t01 = A00*m01 + A01*m11;
            const float t10 = A10*m00 + A11*m10;
            const float t11 = A10*m01 + A11*m11;
            m00 = t00; m01 = t01; m10 = t10; m11 = t11;
        }
        apow[c] = make_float4(m00, m01, m10, m11);
    }
    __syncthreads();

    // ---- phase 2b: Kogge-Stone carry scan (wave 0, lanes 0..31) ----
    // T_c = (A32, f_c); inclusive scan with (Pb,gb)o(Pa,ga) = (Pb Pa, Pb ga + gb).
    // carry[c+1] = P_c * init + g_c  (lane c, c<=30); carry[0] = init.
    if (tid < 32) {
        const int c = tid;
        const float4 A32 = apow[31];
        float P00 = A32.x, P01 = A32.y, P10 = A32.z, P11 = A32.w;
        float g0 = f0, g1 = f1;
        #pragma unroll
        for (int d = 1; d < 32; d <<= 1) {
            const float q00 = __shfl_up(P00, d, 32);
            const float q01 = __shfl_up(P01, d, 32);
            const float q10 = __shfl_up(P10, d, 32);
            const float q11 = __shfl_up(P11, d, 32);
            const float h0  = __shfl_up(g0,  d, 32);
            const float h1  = __shfl_up(g1,  d, 32);
            if (c >= d) {
                const float n00 = P00*q00 + P01*q10;
                const float n01 = P00*q01 + P01*q11;
                const float n10 = P10*q00 + P11*q10;
                const float n11 = P10*q01 + P11*q11;
                g0 = fmaf(P00, h0, fmaf(P01, h1, g0));
                g1 = fmaf(P10, h0, fmaf(P11, h1, g1));
                P00 = n00; P01 = n01; P10 = n10; P11 = n11;
            }
        }
        if (c == 0) {
            carry[0] = make_float2(i0, i1);
            out[(size_t)b * TT * 2 + 0] = i0;   // out[b,0] = init state
            out[(size_t)b * TT * 2 + 1] = i1;
        }
        if (c <= 30)
            carry[c + 1] = make_float2(fmaf(P00, i0, fmaf(P01, i1, g0)),
                                       fmaf(P10, i0, fmaf(P11, i1, g1)));
    }
    __syncthreads();

    // ---- phase 3: out[b,t] = l_{t-1} + A^i * carry_c ----
    const float4 M = apow[tid & 31];            // A^i, i = (t-1)&31 + 1
    float2* outb = reinterpret_cast<float2*>(out + (size_t)b * TT * 2);
    #pragma unroll
    for (int k = 0; k < 4; ++k) {
        const int t = tid + 1 + 256 * k;
        if (t < TT) {
            const int r = t - 1;
            const float2 l  = vbuf[r + (r >> 5)];
            const float2 cr = carry[r >> 5];
            const float o0 = fmaf(M.x, cr.x, fmaf(M.y, cr.y, l.x));
            const float o1 = fmaf(M.z, cr.x, fmaf(M.w, cr.y, l.y));
            outb[t] = make_float2(o0, o1);
        }
    }
}

extern "C" void kernel_launch(void* const* d_in, const int* in_sizes, int n_in,
                              void* d_out, int out_size, void* d_ws, size_t ws_size,
                              hipStream_t stream) {
    const float* init = (const float*)d_in[0];
    const float* z    = (const float*)d_in[1];
    const float* W    = (const float*)d_in[2];
    float*       o    = (float*)d_out;
    ar_decoder_kernel<<<BB, 256, 0, stream>>>(init, z, W, o);
}